// Round 4
// baseline (115.158 us; speedup 1.0000x reference)
//
#include <hip/hip_runtime.h>
#include <hip/hip_bf16.h>

#define NB    2048
#define NUMK  128
#define NE    1024
#define HID   32
#define ROWLEN (NUMK + NE + 2)
#define X1STRIDE 72              // bf16 elems per x1T-half row (64 + 8 pad)
#define A1STRIDE 40              // bf16 elems per a1 row inside Ab span
#define QS 8192.0f               // fixed-point scale 2^13
#define QI (1.0f/8192.0f)

// R4: sparse convert. R3's dense u16->bf16 pass touched all 16384 cells but
// only ~6% are nonzero; untouched fixed-point zeros are ALREADY bf16 zeros.
// Now each edge thread converts only its own cell (self threads the diagonal),
// with read->barrier->write to avoid double-conversion of shared u32s
// (duplicate writers then produce bit-identical values -> benign race).
// The write phase is folded into the x1-half0 build (B3 orders it before the
// MFMA A-reads). a0 = Â·p becomes exact-fp32 edge atomics reusing the nv regs
// that layer-3 needs anyway; p staging deleted; B7 removed (outacc zeroed
// post-B5, self+bias folded into final store); W2 fragments + all small
// params hoisted to P0 (latency hides under build). Barriers 10 -> 9.
// Everything else verbatim from validated R3.

using s8    = __attribute__((ext_vector_type(8))) short;   // 8 bf16 = 16 B
using s4v   = __attribute__((ext_vector_type(4))) short;   // 4 bf16 = 8 B
using f4    = __attribute__((ext_vector_type(4))) float;
using fl4   = __attribute__((ext_vector_type(4))) float;
using u32x4 = __attribute__((ext_vector_type(4))) unsigned;

static __device__ __forceinline__ unsigned short f2bf(float f) {
    unsigned u = __float_as_uint(f);
    unsigned r = (u + 0x7fffu + ((u >> 16) & 1u)) >> 16;   // RNE
    return (unsigned short)r;
}
static __device__ __forceinline__ unsigned cvtpk(float lo, float hi) {
    unsigned r;                                            // D.lo=bf16(lo), D.hi=bf16(hi)
    asm("v_cvt_pk_bf16_f32 %0, %1, %2" : "=v"(r) : "v"(lo), "v"(hi));
    return r;
}
// packed-cell u32 index for (dst row, src col) incl. XOR swizzle
static __device__ __forceinline__ unsigned acell(int d, int s) {
    return (((unsigned)d << 6) + ((unsigned)s >> 1)) ^ (((unsigned)d & 7u) << 2);
}

__global__ __launch_bounds__(512, 8) void gcn_fused_kernel(
    const float* __restrict__ Hx,
    const int*   __restrict__ ei,
    const float* __restrict__ W1, const float* __restrict__ b1,
    const float* __restrict__ W2, const float* __restrict__ b2,
    const float* __restrict__ W3, const float* __restrict__ b3,
    float* __restrict__ out)
{
    __shared__ __align__(16) short Ab[NUMK * 128];          // 32768 B (u32 alias)
    __shared__ __align__(16) short x1h[HID * X1STRIDE];     //  4608 B
    __shared__ float degv[NUMK];                            //   512 B (deg -> dinv)
    __shared__ float a0s[NUMK];                             //   512 B (a0 -> outacc)
    __shared__ float sbuf[NUMK];                            //   512 B (layer-3 s)
    // total 38,912 B -> 4 blocks/CU (thread-capped at 4)

    const int tid = threadIdx.x;                // 0..511
    const int wv = tid >> 6, lane = tid & 63;
    const int l = lane & 15, q = lane >> 4;
    const float* rowp = Hx + (size_t)blockIdx.x * ROWLEN;
    unsigned* Apk = (unsigned*)Ab;
    char*     Abc = (char*)Ab;

    // ---- P0: edge/weight loads + param/W2-frag hoists + zero Apk ----
    const int e0 = tid, e1 = tid + 512;
    const int s0 = ei[e0]      & (NUMK - 1);
    const int d0 = ei[NE + e0] & (NUMK - 1);
    const int s1 = ei[e1]      & (NUMK - 1);
    const int d1 = ei[NE + e1] & (NUMK - 1);
    const float w0 = rowp[NUMK + e0];
    const float w1 = rowp[NUMK + e1];

    union { unsigned u[4]; s8 v; } BW0, BW1;   // W2^T bf16 B-frags (L2-hot)
    #pragma unroll
    for (int j2 = 0; j2 < 4; ++j2) {
        const int krow = (q << 3) + (j2 << 1);
        BW0.u[j2] = cvtpk(W2[(krow << 5) + l],      W2[((krow + 1) << 5) + l]);
        BW1.u[j2] = cvtpk(W2[(krow << 5) + 16 + l], W2[((krow + 1) << 5) + 16 + l]);
    }
    const float w1j = W1[tid >> 4], b1j = b1[tid >> 4];
    const float b2a = b2[l], b2b = b2[l + 16];
    const float w3a = W3[l], w3b = W3[l + 16];
    const float b3v = b3[0];

    {
        const u32x4 z4 = {0u, 0u, 0u, 0u};
        #pragma unroll
        for (int c = 0; c < 4; ++c)
            *(u32x4*)&Apk[(tid << 2) + (c << 11)] = z4;
    }
    if (tid < NUMK) { degv[tid] = 1.0f; a0s[tid] = 0.f; }
    __syncthreads();                                   // BB1

    // ---- P1: scatter raw w (packed u16 fixed) + deg (fp32) ----
    atomicAdd(&Apk[acell(d0, s0)], __float2uint_rn(w0 * QS) << (((unsigned)s0 & 1u) << 4));
    atomicAdd(&Apk[acell(d1, s1)], __float2uint_rn(w1 * QS) << (((unsigned)s1 & 1u) << 4));
    atomicAdd(&degv[d0], w0);
    atomicAdd(&degv[d1], w1);
    if (tid < NUMK)                                    // self-loop, w = 1.0
        atomicAdd(&Apk[acell(tid, tid)], 8192u << (((unsigned)tid & 1u) << 4));
    __syncthreads();                                   // BB2
    if (tid < NUMK) degv[tid] = rsqrtf(degv[tid]);     // deg >= 1 always
    __syncthreads();                                   // BB3

    // ---- P2a: sparse convert READ+COMPUTE (regs) + a0 fp32 atomics ----
    float nv0, nv1;
    unsigned cv0, cv1, cvs = 0;
    unsigned *ap0, *ap1, *aps = nullptr;
    {
        const float dd0 = degv[d0], dd1 = degv[d1];
        nv0 = degv[s0] * w0 * dd0;                     // exact fp32 norms,
        nv1 = degv[s1] * w1 * dd1;                     // reused by layer 3
        ap0 = &Apk[acell(d0, s0)];
        ap1 = &Apk[acell(d1, s1)];
        const unsigned u0 = *ap0, u1 = *ap1;
        const int c0 = s0 & ~1, c1 = s1 & ~1;
        const float sc0 = dd0 * QI, sc1 = dd1 * QI;
        cv0 = cvtpk((float)(u0 & 0xFFFFu) * sc0 * degv[c0],
                    (float)(u0 >> 16)     * sc0 * degv[c0 + 1]);
        cv1 = cvtpk((float)(u1 & 0xFFFFu) * sc1 * degv[c1],
                    (float)(u1 >> 16)     * sc1 * degv[c1 + 1]);
        atomicAdd(&a0s[d0], nv0 * rowp[s0]);
        atomicAdd(&a0s[d1], nv1 * rowp[s1]);
        if (tid < NUMK) {                              // diagonal cell + self a0
            const float dq = degv[tid];
            aps = &Apk[acell(tid, tid)];
            const unsigned us = *aps;
            const int cs = tid & ~1;
            const float scs = dq * QI;
            cvs = cvtpk((float)(us & 0xFFFFu) * scs * degv[cs],
                        (float)(us >> 16)     * scs * degv[cs + 1]);
            atomicAdd(&a0s[tid], dq * dq * rowp[tid]);
        }
    }
    __syncthreads();                                   // BB4 (reads done)

    // ---- layer-2 propagate: a1 = Â @ x1, x1 built in two 64-K halves ----
    f4 accm0 = {0.f,0.f,0.f,0.f}, accm1 = {0.f,0.f,0.f,0.f};
    const int arow = (wv << 4) + l;                    // wave-exclusive Â row
    const int akey = (arow & 7) << 4;                  // byte XOR key
    #pragma unroll
    for (int half = 0; half < 2; ++half) {
        if (half == 0) {                               // P2b: sparse convert WRITE
            *ap0 = cv0;                                // dup writers: identical
            *ap1 = cv1;                                // values -> benign race
            if (tid < NUMK) *aps = cvs;
        }
        {   // build x1h half: x1h[j][k] = relu(a0[64h+k]*w1[j]+b1[j])
            const int kk = (tid & 15) << 2;            // 0..60
            const fl4 av = *(const fl4*)&a0s[(half << 6) + kk];
            union { unsigned u[2]; s4v v; } P;
            P.u[0] = cvtpk(fmaxf(fmaf(av[0], w1j, b1j), 0.f),
                           fmaxf(fmaf(av[1], w1j, b1j), 0.f));
            P.u[1] = cvtpk(fmaxf(fmaf(av[2], w1j, b1j), 0.f),
                           fmaxf(fmaf(av[3], w1j, b1j), 0.f));
            *(s4v*)&x1h[(tid >> 4) * X1STRIDE + kk] = P.v;
        }
        __syncthreads();                               // B3 / B5
        #pragma unroll
        for (int ks2 = 0; ks2 < 2; ++ks2) {
            const int kloc = (ks2 << 5) + (q << 3);
            const s8 A = *(const s8*)(Abc +
                (((arow << 8) + (half << 7) + (ks2 << 6) + (q << 4)) ^ akey));
            const s8 B0 = *(const s8*)&x1h[l * X1STRIDE + kloc];
            const s8 B1 = *(const s8*)&x1h[(16 + l) * X1STRIDE + kloc];
            accm0 = __builtin_amdgcn_mfma_f32_16x16x32_bf16(A, B0, accm0, 0, 0, 0);
            accm1 = __builtin_amdgcn_mfma_f32_16x16x32_bf16(A, B1, accm1, 0, 0, 0);
        }
        if (half == 0) __syncthreads();                // B4 (x1h reads done)
    }

    // ---- a1 -> own Â span (same wave, DS in-order: no barrier; Â now dead) ----
    short* a1w = &Ab[(wv << 4) << 7];                  // 16 Ab rows of this wave
    #pragma unroll
    for (int r = 0; r < 4; ++r) {
        const int tr = (q << 2) + r;
        a1w[tr * A1STRIDE + l]      = (short)f2bf(accm0[r]);
        a1w[tr * A1STRIDE + 16 + l] = (short)f2bf(accm1[r]);
    }
    if (tid < NUMK) a0s[tid] = 0.f;                    // outacc zero (post-B5 safe)

    // ---- P7: x2 = relu(a1@W2+b2); s = x2@W3 (W2 frags hoisted at P0) ----
    {
        const s8 A0 = *(const s8*)&a1w[l * A1STRIDE + (q << 3)];
        f4 ac20 = {0.f,0.f,0.f,0.f}, ac21 = {0.f,0.f,0.f,0.f};
        ac20 = __builtin_amdgcn_mfma_f32_16x16x32_bf16(A0, BW0.v, ac20, 0, 0, 0);
        ac21 = __builtin_amdgcn_mfma_f32_16x16x32_bf16(A0, BW1.v, ac21, 0, 0, 0);
        #pragma unroll
        for (int r = 0; r < 4; ++r) {
            const float v0 = fmaxf(ac20[r] + b2a, 0.f);
            const float v1 = fmaxf(ac21[r] + b2b, 0.f);
            float sv = v0 * w3a + v1 * w3b;
            #pragma unroll
            for (int m = 1; m < 16; m <<= 1) sv += __shfl_xor(sv, m, 16);
            if (l == 0) sbuf[(wv << 4) + (q << 2) + r] = sv;
        }
    }
    __syncthreads();                                   // B6

    // ---- layer-3 propagate, edge-parallel fp32: out = Â·s + b3 ----
    atomicAdd(&a0s[d0], nv0 * sbuf[s0]);
    atomicAdd(&a0s[d1], nv1 * sbuf[s1]);
    __syncthreads();                                   // B8
    if (tid < NUMK) {                                  // + self term + bias
        const float dq = degv[tid];
        out[(size_t)blockIdx.x * NUMK + tid] = a0s[tid] + b3v + dq * dq * sbuf[tid];
    }
}

extern "C" void kernel_launch(void* const* d_in, const int* in_sizes, int n_in,
                              void* d_out, int out_size, void* d_ws, size_t ws_size,
                              hipStream_t stream) {
    const float* Hx = (const float*)d_in[0];
    const int*   ei = (const int*)d_in[1];
    const float* W1 = (const float*)d_in[2];
    const float* b1 = (const float*)d_in[3];
    const float* W2 = (const float*)d_in[4];
    const float* b2 = (const float*)d_in[5];
    const float* W3 = (const float*)d_in[6];
    const float* b3 = (const float*)d_in[7];
    float* out = (float*)d_out;

    (void)d_ws; (void)ws_size;
    gcn_fused_kernel<<<NB, 512, 0, stream>>>(Hx, ei, W1, b1, W2, b2, W3, b3, out);
}

// Round 6
// 113.835 us; speedup vs baseline: 1.0116x; 1.0116x over previous
//
#include <hip/hip_runtime.h>
#include <hip/hip_bf16.h>

#define NB    2048
#define NUMK  128
#define NE    1024
#define HID   32
#define ROWLEN (NUMK + NE + 2)
#define X1STRIDE 72              // bf16 elems per x1T-half row (64 + 8 pad)
#define A1STRIDE 40              // bf16 elems per a1 row inside Ab span
#define QS 8192.0f               // fixed-point scale 2^13
#define QI (1.0f/8192.0f)
#define OBOFF 2048               // out-bank byte offset within wave span (R6 fix)

// R6 = R5 with the out-bank collision fixed.
// R5 bug: out-banks at bytes {128..256,...} of the wave span collided with a1
// (A1STRIDE=40 -> a1 occupies bytes [0,1280) of the span); bank-zeroing
// clobbered a1 before the P7 MFMA read -> absmax 0.145. Now banks live at
// bytes [2048,2560) of each wave's own span: disjoint from a1, still in the
// wave's own rows so barrier-free zeroing via same-wave DS ordering holds.
//  - a0 = Â·p: wave-private 8-bank atomics overlaid on dead x1h region.
//  - deg: 2-banked (degv + dead sbuf), exact fp32.
//  - layer-3 out: wave-private banks at OBOFF in own Ab span.
//  - sparse convert (read cell -> BB4 -> write) + W2/param hoists from R4.
// MFMA skeleton verbatim from validated R3/R4. Barriers: 10.

using s8    = __attribute__((ext_vector_type(8))) short;   // 8 bf16 = 16 B
using s4v   = __attribute__((ext_vector_type(4))) short;   // 4 bf16 = 8 B
using f4    = __attribute__((ext_vector_type(4))) float;
using fl4   = __attribute__((ext_vector_type(4))) float;
using fl2   = __attribute__((ext_vector_type(2))) float;
using u32x4 = __attribute__((ext_vector_type(4))) unsigned;

static __device__ __forceinline__ unsigned short f2bf(float f) {
    unsigned u = __float_as_uint(f);
    unsigned r = (u + 0x7fffu + ((u >> 16) & 1u)) >> 16;   // RNE
    return (unsigned short)r;
}
static __device__ __forceinline__ unsigned cvtpk(float lo, float hi) {
    unsigned r;                                            // D.lo=bf16(lo), D.hi=bf16(hi)
    asm("v_cvt_pk_bf16_f32 %0, %1, %2" : "=v"(r) : "v"(lo), "v"(hi));
    return r;
}
// packed-cell u32 index for (dst row, src col) incl. XOR swizzle
static __device__ __forceinline__ unsigned acell(int d, int s) {
    return (((unsigned)d << 6) + ((unsigned)s >> 1)) ^ (((unsigned)d & 7u) << 2);
}

__global__ __launch_bounds__(512, 8) void gcn_fused_kernel(
    const float* __restrict__ Hx,
    const int*   __restrict__ ei,
    const float* __restrict__ W1, const float* __restrict__ b1,
    const float* __restrict__ W2, const float* __restrict__ b2,
    const float* __restrict__ W3, const float* __restrict__ b3,
    float* __restrict__ out)
{
    __shared__ __align__(16) short Ab[NUMK * 128];          // 32768 B (u32 alias)
    __shared__ __align__(16) short x1h[HID * X1STRIDE];     //  4608 B (pl+a0 banks)
    __shared__ float degv[NUMK];                            //   512 B (deg bank0 -> dinv)
    __shared__ float a0s[NUMK];                             //   512 B (a0 reduced)
    __shared__ float sbuf[NUMK];                            //   512 B (deg bank1 -> s)
    // total 38,912 B -> 4 blocks/CU (thread-capped at 4)

    const int tid = threadIdx.x;                // 0..511
    const int wv = tid >> 6, lane = tid & 63;
    const int l = lane & 15, q = lane >> 4;
    const float* rowp = Hx + (size_t)blockIdx.x * ROWLEN;
    unsigned* Apk = (unsigned*)Ab;
    char*     Abc = (char*)Ab;
    float*    pl  = (float*)x1h;                // [0..128)   p staging
    float*    a0b = (float*)x1h + NUMK;         // 8 banks x 128 f32

    // ---- P0: edge/weight loads + param/W2-frag hoists + zero Apk/a0b ----
    const int e0 = tid, e1 = tid + 512;
    const int s0 = ei[e0]      & (NUMK - 1);
    const int d0 = ei[NE + e0] & (NUMK - 1);
    const int s1 = ei[e1]      & (NUMK - 1);
    const int d1 = ei[NE + e1] & (NUMK - 1);
    const float w0 = rowp[NUMK + e0];
    const float w1 = rowp[NUMK + e1];

    union { unsigned u[4]; s8 v; } BW0, BW1;   // W2^T bf16 B-frags (L2-hot)
    #pragma unroll
    for (int j2 = 0; j2 < 4; ++j2) {
        const int krow = (q << 3) + (j2 << 1);
        BW0.u[j2] = cvtpk(W2[(krow << 5) + l],      W2[((krow + 1) << 5) + l]);
        BW1.u[j2] = cvtpk(W2[(krow << 5) + 16 + l], W2[((krow + 1) << 5) + 16 + l]);
    }
    const float w1j = W1[tid >> 4], b1j = b1[tid >> 4];
    const float b2a = b2[l], b2b = b2[l + 16];
    const float w3a = W3[l], w3b = W3[l + 16];
    const float b3v = b3[0];

    {
        const u32x4 z4 = {0u, 0u, 0u, 0u};
        #pragma unroll
        for (int c = 0; c < 4; ++c)
            *(u32x4*)&Apk[(tid << 2) + (c << 11)] = z4;
    }
    a0b[tid] = 0.f; a0b[tid + 512] = 0.f;              // zero a0 banks
    if (tid < NUMK) { degv[tid] = 1.0f; sbuf[tid] = 0.f; pl[tid] = rowp[tid]; }
    __syncthreads();                                   // BB1

    // ---- P1: scatter raw w (packed u16 fixed) + deg (2-banked fp32) ----
    atomicAdd(&Apk[acell(d0, s0)], __float2uint_rn(w0 * QS) << (((unsigned)s0 & 1u) << 4));
    atomicAdd(&Apk[acell(d1, s1)], __float2uint_rn(w1 * QS) << (((unsigned)s1 & 1u) << 4));
    {
        float* dbank = (tid & 256) ? sbuf : degv;      // wave-uniform select
        atomicAdd(&dbank[d0], w0);
        atomicAdd(&dbank[d1], w1);
    }
    if (tid < NUMK)                                    // self-loop, w = 1.0
        atomicAdd(&Apk[acell(tid, tid)], 8192u << (((unsigned)tid & 1u) << 4));
    __syncthreads();                                   // BB2
    if (tid < NUMK) degv[tid] = rsqrtf(degv[tid] + sbuf[tid]);  // deg >= 1
    __syncthreads();                                   // BB3

    // ---- P2a: sparse convert READ+COMPUTE + a0 wave-private atomics ----
    float nv0, nv1;
    unsigned cv0, cv1, cvs = 0;
    unsigned *ap0, *ap1, *aps = nullptr;
    {
        const float dd0 = degv[d0], dd1 = degv[d1];
        nv0 = degv[s0] * w0 * dd0;                     // exact fp32 norms,
        nv1 = degv[s1] * w1 * dd1;                     // reused by layer 3
        ap0 = &Apk[acell(d0, s0)];
        ap1 = &Apk[acell(d1, s1)];
        const unsigned u0 = *ap0, u1 = *ap1;
        const int c0 = s0 & ~1, c1 = s1 & ~1;
        const float sc0 = dd0 * QI, sc1 = dd1 * QI;
        cv0 = cvtpk((float)(u0 & 0xFFFFu) * sc0 * degv[c0],
                    (float)(u0 >> 16)     * sc0 * degv[c0 + 1]);
        cv1 = cvtpk((float)(u1 & 0xFFFFu) * sc1 * degv[c1],
                    (float)(u1 >> 16)     * sc1 * degv[c1 + 1]);
        float* ab = a0b + (wv << 7);                   // own wave's bank
        atomicAdd(&ab[d0], nv0 * pl[s0]);
        atomicAdd(&ab[d1], nv1 * pl[s1]);
        if (tid < NUMK) {                              // diagonal cell convert
            const float dq = degv[tid];
            aps = &Apk[acell(tid, tid)];
            const unsigned us = *aps;
            const int cs = tid & ~1;
            const float scs = dq * QI;
            cvs = cvtpk((float)(us & 0xFFFFu) * scs * degv[cs],
                        (float)(us >> 16)     * scs * degv[cs + 1]);
        }
    }
    __syncthreads();                                   // BB4 (reads+atomics done)

    // ---- P2b: sparse convert WRITE (dup writers identical) + a0 reduce ----
    *ap0 = cv0;
    *ap1 = cv1;
    if (tid < NUMK) {
        *aps = cvs;
        const float dq = degv[tid];
        float a = dq * dq * pl[tid];                   // self term
        #pragma unroll
        for (int k = 0; k < 8; ++k) a += a0b[(k << 7) + tid];
        a0s[tid] = a;
    }
    __syncthreads();                                   // B4b (a0s ready; overlay dead)

    // ---- layer-2 propagate: a1 = Â @ x1, x1 built in two 64-K halves ----
    f4 accm0 = {0.f,0.f,0.f,0.f}, accm1 = {0.f,0.f,0.f,0.f};
    const int arow = (wv << 4) + l;                    // wave-exclusive Â row
    const int akey = (arow & 7) << 4;                  // byte XOR key
    #pragma unroll
    for (int half = 0; half < 2; ++half) {
        {   // build x1h half: x1h[j][k] = relu(a0[64h+k]*w1[j]+b1[j])
            const int kk = (tid & 15) << 2;            // 0..60
            const fl4 av = *(const fl4*)&a0s[(half << 6) + kk];
            union { unsigned u[2]; s4v v; } P;
            P.u[0] = cvtpk(fmaxf(fmaf(av[0], w1j, b1j), 0.f),
                           fmaxf(fmaf(av[1], w1j, b1j), 0.f));
            P.u[1] = cvtpk(fmaxf(fmaf(av[2], w1j, b1j), 0.f),
                           fmaxf(fmaf(av[3], w1j, b1j), 0.f));
            *(s4v*)&x1h[(tid >> 4) * X1STRIDE + kk] = P.v;
        }
        __syncthreads();                               // B3 / B5
        #pragma unroll
        for (int ks2 = 0; ks2 < 2; ++ks2) {
            const int kloc = (ks2 << 5) + (q << 3);
            const s8 A = *(const s8*)(Abc +
                (((arow << 8) + (half << 7) + (ks2 << 6) + (q << 4)) ^ akey));
            const s8 B0 = *(const s8*)&x1h[l * X1STRIDE + kloc];
            const s8 B1 = *(const s8*)&x1h[(16 + l) * X1STRIDE + kloc];
            accm0 = __builtin_amdgcn_mfma_f32_16x16x32_bf16(A, B0, accm0, 0, 0, 0);
            accm1 = __builtin_amdgcn_mfma_f32_16x16x32_bf16(A, B1, accm1, 0, 0, 0);
        }
        if (half == 0) __syncthreads();                // B4 (x1h reads done)
    }

    // ---- a1 -> own Â span bytes [0,1280) + zero own out-bank [2048,2560) ----
    // Same wave's A-reads precede these writes in DS order: no barrier needed.
    short* a1w = &Ab[(wv << 4) << 7];                  // 16 Ab rows of this wave
    #pragma unroll
    for (int r = 0; r < 4; ++r) {
        const int tr = (q << 2) + r;
        a1w[tr * A1STRIDE + l]      = (short)f2bf(accm0[r]);
        a1w[tr * A1STRIDE + 16 + l] = (short)f2bf(accm1[r]);
    }
    {   // out-bank of wave wv: 128 f32 at span bytes [OBOFF, OBOFF+512)
        const fl2 z2 = {0.f, 0.f};
        *(fl2*)(Abc + (wv << 12) + OBOFF + (lane << 3)) = z2;
    }

    // ---- P7: x2 = relu(a1@W2+b2); s = x2@W3 (W2 frags hoisted at P0) ----
    {
        const s8 A0 = *(const s8*)&a1w[l * A1STRIDE + (q << 3)];
        f4 ac20 = {0.f,0.f,0.f,0.f}, ac21 = {0.f,0.f,0.f,0.f};
        ac20 = __builtin_amdgcn_mfma_f32_16x16x32_bf16(A0, BW0.v, ac20, 0, 0, 0);
        ac21 = __builtin_amdgcn_mfma_f32_16x16x32_bf16(A0, BW1.v, ac21, 0, 0, 0);
        #pragma unroll
        for (int r = 0; r < 4; ++r) {
            const float v0 = fmaxf(ac20[r] + b2a, 0.f);
            const float v1 = fmaxf(ac21[r] + b2b, 0.f);
            float sv = v0 * w3a + v1 * w3b;
            #pragma unroll
            for (int m = 1; m < 16; m <<= 1) sv += __shfl_xor(sv, m, 16);
            if (l == 0) sbuf[(wv << 4) + (q << 2) + r] = sv;
        }
    }
    __syncthreads();                                   // B6 (sbuf + bank zeros visible)

    // ---- layer-3 propagate: wave-private out-bank atomics (fp32 exact) ----
    {
        float* ow = (float*)(Abc + (wv << 12) + OBOFF);  // own wave's bank
        atomicAdd(&ow[d0], nv0 * sbuf[s0]);
        atomicAdd(&ow[d1], nv1 * sbuf[s1]);
    }
    __syncthreads();                                   // B8

    if (tid < NUMK) {                                  // sum banks + self + bias
        const float dq = degv[tid];
        float acc = b3v + dq * dq * sbuf[tid];
        #pragma unroll
        for (int k = 0; k < 8; ++k)
            acc += ((const float*)(Abc + (k << 12) + OBOFF))[tid];
        out[(size_t)blockIdx.x * NUMK + tid] = acc;
    }
}

extern "C" void kernel_launch(void* const* d_in, const int* in_sizes, int n_in,
                              void* d_out, int out_size, void* d_ws, size_t ws_size,
                              hipStream_t stream) {
    const float* Hx = (const float*)d_in[0];
    const int*   ei = (const int*)d_in[1];
    const float* W1 = (const float*)d_in[2];
    const float* b1 = (const float*)d_in[3];
    const float* W2 = (const float*)d_in[4];
    const float* b2 = (const float*)d_in[5];
    const float* W3 = (const float*)d_in[6];
    const float* b3 = (const float*)d_in[7];
    float* out = (float*)d_out;

    (void)d_ws; (void)ws_size;
    gcn_fused_kernel<<<NB, 512, 0, stream>>>(Hx, ei, W1, b1, W2, b2, W3, b3, out);
}

// Round 7
// 102.276 us; speedup vs baseline: 1.1259x; 1.1130x over previous
//
#include <hip/hip_runtime.h>
#include <hip/hip_bf16.h>

#define NB    2048
#define NUMK  128
#define NE    1024
#define HID   32
#define ROWLEN (NUMK + NE + 2)
#define CAP   24                 // padded slots per row (unique srcs + self)
#define NPS   (NUMK * CAP)       // 3072
#define X1STRIDE 72              // bf16 elems per x1T-half row (64 + 8 pad)
#define A1STRIDE 40              // bf16 elems per a1 row inside Ab span
#define W2STRIDE 40              // bf16 elems per w2tg row (32 + 8 pad)
#define WSELF 1024               // widx of self-loop weight (1.0)
#define WPAD  1025               // widx of pad weight (0.0)
#define WVBASE 1026              // first vslot (chained dup merges)
#define MAXV  16

// R7: return to the R0 two-kernel structure (best measured main kernel) with
// the micro-opts validated in R3-R6. Ledger: R0 main ~31us (slot tables from
// d_ws, NO per-block build, no LDS atomics, 6 barriers) vs fused variants
// 41-48us -- per-block rebuild cost dominates any fusion gain, and the ~66us
// harness gap is unconditional (identical whether d_ws is written or not).
// Changes vs R0 main:
//  - ASTRIDE 136 -> 128 + XOR swizzle byte^=((row&7)<<4) (R6-validated
//    addressing): LDS 40448 -> 38400 B (R0 was within 2KB of the 4-block
//    LDS cap), fewer conflicts on Â scatter/read.
//  - v_cvt_pk_bf16_f32 for x1 packing (R3+-validated), param hoists to P0.
//  - __launch_bounds__(512,8) pins the 4-block/CU register budget.
// Build kernel verbatim from validated R0.

using s8  = __attribute__((ext_vector_type(8))) short;   // 8 bf16 = 16 B
using s4v = __attribute__((ext_vector_type(4))) short;   // 4 bf16 = 8 B
using f4  = __attribute__((ext_vector_type(4))) float;
using fl4 = __attribute__((ext_vector_type(4))) float;

static __device__ __forceinline__ unsigned short f2bf(float f) {
    unsigned u = __float_as_uint(f);
    unsigned r = (u + 0x7fffu + ((u >> 16) & 1u)) >> 16;   // RNE
    return (unsigned short)r;
}
static __device__ __forceinline__ unsigned cvtpk(float lo, float hi) {
    unsigned r;                                            // D.lo=bf16(lo), D.hi=bf16(hi)
    asm("v_cvt_pk_bf16_f32 %0, %1, %2" : "=v"(r) : "v"(lo), "v"(hi));
    return r;
}

// resolve a weight index (raw eid / WSELF / WPAD / vslot chain) from global
static __device__ __forceinline__ float wload(const float* __restrict__ rowp,
                                              unsigned idx,
                                              const unsigned* __restrict__ vmeta) {
    float w = 0.f;
    while (idx >= (unsigned)WVBASE) {                  // rare: >=3-dup chains
        const unsigned e = vmeta[1 + (idx - (unsigned)WVBASE)];
        const unsigned b = e >> 11;
        w += (b < 1024u) ? rowp[NUMK + b] : (b == (unsigned)WSELF ? 1.0f : 0.0f);
        idx = e & 0x7FFu;
    }
    w += (idx < 1024u) ? rowp[NUMK + idx] : (idx == (unsigned)WSELF ? 1.0f : 0.0f);
    return w;
}

// ---------------------------------------------------------------------------
// Setup (once): CSR by dst, per-row dedup into (widx, widx2 [, vslot chain]);
// pre-pack W2^T bf16 B-frag layout into ws. (Validated R0/R12 code, verbatim.)
// ---------------------------------------------------------------------------
__global__ __launch_bounds__(1024) void build_csr_kernel(
    const int* __restrict__ ei,
    const float* __restrict__ W2,
    unsigned* __restrict__ pslot_g,    // [NPS]
    short* __restrict__ w2tg,          // [HID * W2STRIDE]
    unsigned* __restrict__ vmeta_g)    // [1 + MAXV]
{
    __shared__ unsigned cnt[NUMK], roff[NUMK + 1], cur[NUMK], incl[NUMK];
    __shared__ unsigned pk[NE];
    __shared__ unsigned psl[NUMK][CAP];
    __shared__ unsigned vc;
    const int t = threadIdx.x;

    if (t < NUMK) cnt[t] = 0u;
    if (t == 0) vc = 0u;
    {   // W2^T bf16 pack: w2tg[n*40+k] = bf16(W2[k*32+n])
        const int k = t >> 5, n = t & 31;
        w2tg[n * W2STRIDE + k] = (short)f2bf(W2[t]);
    }
    __syncthreads();
    const int dst = ei[NE + t] & (NUMK - 1);
    atomicAdd(&cnt[dst], 1u);
    __syncthreads();

    if (t < NUMK) {                              // exclusive scan (2 wave scans)
        unsigned v = cnt[t];
        #pragma unroll
        for (int d = 1; d < 64; d <<= 1) {
            unsigned u = __shfl_up(v, d, 64);
            if ((t & 63) >= d) v += u;
        }
        incl[t] = v;
    }
    __syncthreads();
    if (t < NUMK) {
        const unsigned base = (t >= 64) ? incl[63] : 0u;
        const unsigned off  = base + incl[t] - cnt[t];
        roff[t] = off; cur[t] = off;
    }
    if (t == 0) roff[NUMK] = (unsigned)NE;
    __syncthreads();

    {
        const int src = ei[t] & (NUMK - 1);
        const unsigned pos = atomicAdd(&cur[dst], 1u);
        pk[pos] = (unsigned)src | ((unsigned)t << 16);
    }
    __syncthreads();

    if (t < NUMK) {
        int np = 0;
        auto addOrMerge = [&](unsigned s, unsigned eid) {
            int j = -1;
            for (int i = 0; i < np; ++i)
                if ((psl[t][i] & 127u) == s) { j = i; break; }
            if (j >= 0) {
                const unsigned slot = psl[t][j];
                const unsigned w2x = (slot >> 18) & 0x7FFu;
                if (w2x == (unsigned)WPAD) {
                    psl[t][j] = (slot & ~(0x7FFu << 18)) | (eid << 18);
                } else {
                    const unsigned v = atomicAdd(&vc, 1u);
                    if (v < (unsigned)MAXV) {
                        vmeta_g[1 + v] = w2x | (eid << 11);
                        psl[t][j] = (slot & ~(0x7FFu << 18))
                                  | (((unsigned)WVBASE + v) << 18);
                    }
                }
            } else if (np < CAP) {
                psl[t][np++] = s | (eid << 7)
                             | ((unsigned)WPAD << 18) | (1u << 29);
            }
        };
        const unsigned k0 = roff[t], k1 = roff[t + 1];
        for (unsigned k = k0; k < k1; ++k)
            addOrMerge(pk[k] & 127u, pk[k] >> 16);
        addOrMerge((unsigned)t, (unsigned)WSELF);        // self-loop, w = 1
        for (int i = np; i < CAP; ++i)                   // pads: w = 0, prim = 0
            psl[t][i] = ((unsigned)WPAD << 7) | ((unsigned)WPAD << 18);
    }
    __syncthreads();

    for (int i = t; i < NPS; i += 1024) {
        const int e = i >> 9, rem = i & 511;
        const int r = rem >> 2, l4i = rem & 3;
        pslot_g[i] = psl[r][l4i * 6 + e];
    }
    if (t == 0) vmeta_g[0] = (vc <= (unsigned)MAXV) ? vc : (unsigned)MAXV;
}

// ---------------------------------------------------------------------------
// Main: one block (512 thr = 8 waves) per graph; 38,400 B LDS -> 4 blocks/CU.
// Slot tables from d_ws; weights/signals read straight from the L1-hot Hx
// row; no LDS atomics; 6 barriers. MFMA skeleton from validated R0/R6.
// ---------------------------------------------------------------------------
__global__ __launch_bounds__(512, 8) void gcn_main_kernel(
    const float* __restrict__ Hx,
    const float* __restrict__ W1, const float* __restrict__ b1,
    const float* __restrict__ b2, const float* __restrict__ W3,
    const float* __restrict__ b3,
    const unsigned* __restrict__ pslot_g,
    const short*    __restrict__ w2tg,
    const unsigned* __restrict__ vmeta_g,
    float* __restrict__ out)
{
    __shared__ __align__(16) short Ab[NUMK * 128];        // 32768 B
    __shared__ __align__(16) short x1h[HID * X1STRIDE];   //  4608 B
    __shared__ float degv[NUMK];                          //   512 B (dinv->sbuf)
    __shared__ float a0s[NUMK];                           //   512 B
    // total 38,400 B -> 4 blocks/CU

    const int tid = threadIdx.x;                // 0..511
    const int row = tid >> 2, l4 = tid & 3;     // 128 rows x 4 lanes
    const int wv = tid >> 6, lane = tid & 63;
    const int l = lane & 15, q = lane >> 4;
    const float* rowp = Hx + (size_t)blockIdx.x * ROWLEN;
    char* Abc = (char*)Ab;

    // ---- P0: slot loads + param hoists + zero A^ (independent; overlap) ----
    unsigned su[6];
    #pragma unroll
    for (int e = 0; e < 6; ++e) su[e] = pslot_g[(e << 9) + tid];
    const float w1j = W1[tid >> 4], b1j = b1[tid >> 4];   // L2-hot
    const float b2a = b2[l], b2b = b2[l + 16];
    const float w3a = W3[l], w3b = W3[l + 16];
    const float b3v = b3[0];
    for (int t2 = tid; t2 < (NUMK * 128) / 8; t2 += 512)
        *(s8*)&Ab[t2 * 8] = (s8)0;

    // ---- P2: merged slot weights from GLOBAL + deg -> dinv ----
    float nvr[6];
    {
        float d = 0.f;
        #pragma unroll
        for (int e = 0; e < 6; ++e) {
            const unsigned u = su[e];
            nvr[e] = wload(rowp, (u >> 7) & 0x7FFu, vmeta_g)
                   + wload(rowp, (u >> 18) & 0x7FFu, vmeta_g);
            d += nvr[e];
        }
        d += __shfl_xor(d, 1, 4);
        d += __shfl_xor(d, 2, 4);
        if (l4 == 0) degv[row] = rsqrtf(d);            // deg >= 1 (self w=1)
    }
    __syncthreads();                                   // B1

    // ---- P4: norms + A^ scatter (own row, swizzled) + a0 = A^·p ----
    {
        const float dr = degv[row];
        const int rkey = (row & 7) << 4;               // byte XOR key
        float acc = 0.f;
        #pragma unroll
        for (int e = 0; e < 6; ++e) {
            const unsigned u = su[e];
            const int s = (int)(u & 127u);
            const float nv = (u >> 29) ? dr * degv[s] * nvr[e] : 0.f;
            if (u >> 29)
                *(short*)(Abc + (((row << 8) + (s << 1)) ^ rkey)) = (short)f2bf(nv);
            nvr[e] = nv;
            acc = fmaf(nv, rowp[s], acc);              // p[s] from L1-hot row
        }
        acc += __shfl_xor(acc, 1, 4);
        acc += __shfl_xor(acc, 2, 4);
        if (l4 == 0) a0s[row] = acc;
    }
    __syncthreads();                                   // B2

    // ---- layer-2 propagate: a1 = A^ @ x1, x1 built in two 64-K halves ----
    f4 accm0 = {0.f,0.f,0.f,0.f}, accm1 = {0.f,0.f,0.f,0.f};
    const int arow = (wv << 4) + l;                    // wave-exclusive A^ row
    const int akey = (arow & 7) << 4;                  // byte XOR key
    #pragma unroll
    for (int half = 0; half < 2; ++half) {
        {   // build x1h half: x1h[j][k] = relu(a0[64h+k]*w1[j]+b1[j])
            const int kk = (tid & 15) << 2;            // 0..60
            const fl4 av = *(const fl4*)&a0s[(half << 6) + kk];
            union { unsigned u[2]; s4v v; } P;
            P.u[0] = cvtpk(fmaxf(fmaf(av[0], w1j, b1j), 0.f),
                           fmaxf(fmaf(av[1], w1j, b1j), 0.f));
            P.u[1] = cvtpk(fmaxf(fmaf(av[2], w1j, b1j), 0.f),
                           fmaxf(fmaf(av[3], w1j, b1j), 0.f));
            *(s4v*)&x1h[(tid >> 4) * X1STRIDE + kk] = P.v;
        }
        __syncthreads();                               // B3 / B5
        #pragma unroll
        for (int ks2 = 0; ks2 < 2; ++ks2) {
            const int kloc = (ks2 << 5) + (q << 3);
            const s8 A = *(const s8*)(Abc +
                (((arow << 8) + (half << 7) + (ks2 << 6) + (q << 4)) ^ akey));
            const s8 B0 = *(const s8*)&x1h[l * X1STRIDE + kloc];
            const s8 B1 = *(const s8*)&x1h[(16 + l) * X1STRIDE + kloc];
            accm0 = __builtin_amdgcn_mfma_f32_16x16x32_bf16(A, B0, accm0, 0, 0, 0);
            accm1 = __builtin_amdgcn_mfma_f32_16x16x32_bf16(A, B1, accm1, 0, 0, 0);
        }
        if (half == 0) __syncthreads();                // B4 (x1h reads done)
    }

    // ---- a1 -> own A^ span (same wave, DS in-order: no barrier) ----
    short* a1w = &Ab[(wv << 4) << 7];                  // 16 Ab rows of this wave
    #pragma unroll
    for (int r = 0; r < 4; ++r) {
        const int tr = (q << 2) + r;
        a1w[tr * A1STRIDE + l]      = (short)f2bf(accm0[r]);
        a1w[tr * A1STRIDE + 16 + l] = (short)f2bf(accm1[r]);
    }

    // ---- P7: x2 = relu(a1@W2+b2); s = x2@W3 (W2 frags from d_ws, L2-hot) ----
    {
        const s8 A0  = *(const s8*)&a1w[l * A1STRIDE + (q << 3)];
        const s8 Bw0 = *(const s8*)&w2tg[l * W2STRIDE + (q << 3)];
        const s8 Bw1 = *(const s8*)&w2tg[(16 + l) * W2STRIDE + (q << 3)];
        f4 ac20 = {0.f,0.f,0.f,0.f}, ac21 = {0.f,0.f,0.f,0.f};
        ac20 = __builtin_amdgcn_mfma_f32_16x16x32_bf16(A0, Bw0, ac20, 0, 0, 0);
        ac21 = __builtin_amdgcn_mfma_f32_16x16x32_bf16(A0, Bw1, ac21, 0, 0, 0);

        float* sbuf = degv;                            // dinv dead after P4
        #pragma unroll
        for (int r = 0; r < 4; ++r) {
            const float v0 = fmaxf(ac20[r] + b2a, 0.f);
            const float v1 = fmaxf(ac21[r] + b2b, 0.f);
            float sv = v0 * w3a + v1 * w3b;
            #pragma unroll
            for (int m = 1; m < 16; m <<= 1) sv += __shfl_xor(sv, m, 16);
            if (l == 0) sbuf[(wv << 4) + (q << 2) + r] = sv;
        }
    }
    __syncthreads();                                   // B6

    // ---- P8: out = A^·s (norms + slots from regs) ----
    {
        float* sbuf = degv;
        float acc8 = 0.f;
        #pragma unroll
        for (int e = 0; e < 6; ++e)
            acc8 = fmaf(nvr[e], sbuf[su[e] & 127u], acc8);
        acc8 += __shfl_xor(acc8, 1, 4);
        acc8 += __shfl_xor(acc8, 2, 4);
        if (l4 == 0) out[(size_t)blockIdx.x * NUMK + row] = acc8 + b3v;
    }
}

extern "C" void kernel_launch(void* const* d_in, const int* in_sizes, int n_in,
                              void* d_out, int out_size, void* d_ws, size_t ws_size,
                              hipStream_t stream) {
    const float* Hx = (const float*)d_in[0];
    const int*   ei = (const int*)d_in[1];
    const float* W1 = (const float*)d_in[2];
    const float* b1 = (const float*)d_in[3];
    const float* W2 = (const float*)d_in[4];
    const float* b2 = (const float*)d_in[5];
    const float* W3 = (const float*)d_in[6];
    const float* b3 = (const float*)d_in[7];
    float* out = (float*)d_out;

    unsigned* pslot = (unsigned*)d_ws;                 // [3072]   12288 B
    short*    w2tg  = (short*)(pslot + NPS);           // [1280]    2560 B
    unsigned* vmeta = (unsigned*)(w2tg + HID * W2STRIDE); // [1+MAXV]

    build_csr_kernel<<<1, 1024, 0, stream>>>(ei, W2, pslot, w2tg, vmeta);
    gcn_main_kernel<<<NB, 512, 0, stream>>>(Hx, W1, b1, b2, W3, b3,
                                            pslot, w2tg, vmeta, out);
}